// Round 1
// baseline (1582.972 us; speedup 1.0000x reference)
//
#include <hip/hip_runtime.h>
#include <math.h>

#define D_MODEL 1024
#define N_HEADS 16
#define D_K 64
#define B_SZ 64
#define S_LEN 2048

// ---------------- kernel 0: qh[b,n] = q[b,:] @ Wq[:,n] + bq[n] ----------------
// grid 256 = (64 b x 4 n-chunks), block 256
__global__ __launch_bounds__(256) void k_qh(const float* __restrict__ q,
                                            const float* __restrict__ Wq,
                                            const float* __restrict__ bq,
                                            float* __restrict__ qh) {
    int b = blockIdx.x >> 2;
    int nc = blockIdx.x & 3;
    int t = threadIdx.x;
    __shared__ float ql[D_MODEL];
    ((float4*)ql)[t] = ((const float4*)(q + (size_t)b * D_MODEL))[t];
    __syncthreads();
    int n = nc * 256 + t;
    const float* w = Wq + n;
    float acc = 0.f;
#pragma unroll 8
    for (int d = 0; d < D_MODEL; ++d) acc = fmaf(ql[d], w[(size_t)d * D_MODEL], acc);
    qh[(size_t)b * D_MODEL + n] = acc + bq[n];
}

// ---------------- kernel 1: qt[b,h,d] = (1/8) * sum_j qh[b,h*64+j] * Wk[d, h*64+j] ----------------
// grid 1024 = (b,h), block 256; thread covers d = t + 256p
__global__ __launch_bounds__(256) void k_qtil(const float* __restrict__ qh,
                                              const float* __restrict__ Wk,
                                              float* __restrict__ qt) {
    int b = blockIdx.x >> 4;
    int h = blockIdx.x & 15;
    int t = threadIdx.x;
    __shared__ float qhl[D_K];
    if (t < 16) ((float4*)qhl)[t] = ((const float4*)(qh + (size_t)b * D_MODEL + h * D_K))[t];
    __syncthreads();
#pragma unroll
    for (int p = 0; p < 4; ++p) {
        int d = p * 256 + t;
        const float* w = Wk + (size_t)d * D_MODEL + h * D_K;
        float acc = 0.f;
#pragma unroll
        for (int j4 = 0; j4 < 16; ++j4) {
            float4 w4 = ((const float4*)w)[j4];
            float4 q4 = ((const float4*)qhl)[j4];
            acc += w4.x * q4.x + w4.y * q4.y + w4.z * q4.z + w4.w * q4.w;
        }
        qt[((size_t)(b * N_HEADS + h)) * D_MODEL + d] = acc * 0.125f;
    }
}

// ---------------- kernel 2: fused flash-decode chunk ----------------
// grid 1024 = (64 b x 16 s-chunks of 128), block 256 = 4 waves.
// Phase A: scores[s,h] for the chunk (wave w -> heads 4w..4w+3; lane owns s=lane,64+lane)
// Phase B: per-head chunk max m / sum l, p = exp(s-m) -> LDS
// Phase C: partial AV over full D_MODEL v rows; writes part + (m,l)
#define NCH 16
#define CS 128
#define DCA 64
#define KROWA 68  // 64 + 4 pad: b128 quad = (row + d4) % 8 -> even bank spread
__global__ __launch_bounds__(256, 4) void k_attn(const float* __restrict__ k,
                                                 const float* __restrict__ v,
                                                 const float* __restrict__ qt,
                                                 float* __restrict__ part,
                                                 float* __restrict__ ml) {
    __shared__ float smem[CS * KROWA + N_HEADS * DCA];  // 38.9 KB -> 4 blocks/CU
    float* kt = smem;
    float* qtl = smem + CS * KROWA;
    float* pl = smem;  // aliases kt region after score phase (8 KB << 34 KB)

    int b = blockIdx.x >> 4;
    int ch = blockIdx.x & 15;
    int t = threadIdx.x;
    int w = t >> 6, lane = t & 63;
    int s0 = ch * CS;
    const float* kbase = k + ((size_t)b * S_LEN + s0) * D_MODEL;
    const float* qtbase = qt + (size_t)b * N_HEADS * D_MODEL;

    float acc[2][4] = {};
    for (int dc = 0; dc < D_MODEL; dc += DCA) {
        // stage K tile: 128 s x 64 d ; 8 float4/thread ; 16 lanes per row (256B segs)
#pragma unroll
        for (int p = 0; p < 8; ++p) {
            int idx = t + 256 * p;
            int s = idx >> 4, d4 = idx & 15;
            float4 x = *(const float4*)(kbase + (size_t)s * D_MODEL + dc + 4 * d4);
            *(float4*)(kt + s * KROWA + 4 * d4) = x;
        }
        // stage qt tile: 16 h x 64 d (one float4 per thread)
        {
            int h = t >> 4, d4 = t & 15;
            *(float4*)(qtl + h * DCA + 4 * d4) =
                *(const float4*)(qtbase + (size_t)h * D_MODEL + dc + 4 * d4);
        }
        __syncthreads();
#pragma unroll
        for (int d4 = 0; d4 < DCA / 4; ++d4) {
            float4 qv[4], kv[2];
#pragma unroll
            for (int j = 0; j < 4; ++j) qv[j] = *(const float4*)(qtl + (4 * w + j) * DCA + 4 * d4);
#pragma unroll
            for (int i = 0; i < 2; ++i) kv[i] = *(const float4*)(kt + (64 * i + lane) * KROWA + 4 * d4);
#pragma unroll
            for (int i = 0; i < 2; ++i)
#pragma unroll
                for (int j = 0; j < 4; ++j)
                    acc[i][j] = fmaf(kv[i].x, qv[j].x,
                                fmaf(kv[i].y, qv[j].y,
                                fmaf(kv[i].z, qv[j].z,
                                fmaf(kv[i].w, qv[j].w, acc[i][j]))));
        }
        __syncthreads();
    }
    // ---- phase B: per-head chunk softmax partials (head 4w+j owned by wave w) ----
#pragma unroll
    for (int j = 0; j < 4; ++j) {
        float m = fmaxf(acc[0][j], acc[1][j]);
#pragma unroll
        for (int o = 32; o; o >>= 1) m = fmaxf(m, __shfl_xor(m, o, 64));
        float p0 = __expf(acc[0][j] - m);
        float p1 = __expf(acc[1][j] - m);
        float l = p0 + p1;
#pragma unroll
        for (int o = 32; o; o >>= 1) l += __shfl_xor(l, o, 64);
        int h = 4 * w + j;
        pl[h * CS + lane] = p0;
        pl[h * CS + 64 + lane] = p1;
        if (lane == 0) {
            float* mlp = ml + ((((size_t)ch * B_SZ) + b) * N_HEADS + h) * 2;
            mlp[0] = m;
            mlp[1] = l;
        }
    }
    __syncthreads();
    // ---- phase C: partial AV; thread owns d-float4 = 4t..4t+3; 16 head accums ----
    float4 oacc[N_HEADS];
#pragma unroll
    for (int h = 0; h < N_HEADS; ++h) oacc[h] = make_float4(0.f, 0.f, 0.f, 0.f);
    const float* vbase = v + ((size_t)b * S_LEN + s0) * D_MODEL + 4 * t;
    for (int sg = 0; sg < CS / 4; ++sg) {
        float4 v0 = *(const float4*)(vbase + (size_t)(4 * sg + 0) * D_MODEL);
        float4 v1 = *(const float4*)(vbase + (size_t)(4 * sg + 1) * D_MODEL);
        float4 v2 = *(const float4*)(vbase + (size_t)(4 * sg + 2) * D_MODEL);
        float4 v3 = *(const float4*)(vbase + (size_t)(4 * sg + 3) * D_MODEL);
#pragma unroll
        for (int h = 0; h < N_HEADS; ++h) {
            float4 a4 = *(const float4*)(pl + h * CS + 4 * sg);  // broadcast read
            oacc[h].x = fmaf(a4.x, v0.x, fmaf(a4.y, v1.x, fmaf(a4.z, v2.x, fmaf(a4.w, v3.x, oacc[h].x))));
            oacc[h].y = fmaf(a4.x, v0.y, fmaf(a4.y, v1.y, fmaf(a4.z, v2.y, fmaf(a4.w, v3.y, oacc[h].y))));
            oacc[h].z = fmaf(a4.x, v0.z, fmaf(a4.y, v1.z, fmaf(a4.z, v2.z, fmaf(a4.w, v3.z, oacc[h].z))));
            oacc[h].w = fmaf(a4.x, v0.w, fmaf(a4.y, v1.w, fmaf(a4.z, v2.w, fmaf(a4.w, v3.w, oacc[h].w))));
        }
    }
#pragma unroll
    for (int h = 0; h < N_HEADS; ++h)
        *(float4*)(part + ((((size_t)ch * B_SZ) + b) * N_HEADS + h) * D_MODEL + 4 * t) = oacc[h];
}

// ---------------- kernel 3: cross-chunk combine + Wv projection ----------------
// grid 1024 = (b,h), block 64 (1 wave)
// vt[d] = (1/L) * sum_ch exp(m_ch - M) * part[ch,b,h,d]; cc = vt @ Wv[:,h64+lane] + bv
__global__ __launch_bounds__(64) void k_cc(const float* __restrict__ part,
                                           const float* __restrict__ ml,
                                           const float* __restrict__ Wv,
                                           const float* __restrict__ bv,
                                           float* __restrict__ cc) {
    int b = blockIdx.x >> 4, h = blockIdx.x & 15;
    int lane = threadIdx.x;
    __shared__ float vt[D_MODEL];
    float m[NCH], lw[NCH];
    float M = -3.4e38f;
#pragma unroll
    for (int ch = 0; ch < NCH; ++ch) {
        const float* mlp = ml + ((((size_t)ch * B_SZ) + b) * N_HEADS + h) * 2;
        m[ch] = mlp[0];
        lw[ch] = mlp[1];
        M = fmaxf(M, m[ch]);
    }
    float L = 0.f;
#pragma unroll
    for (int ch = 0; ch < NCH; ++ch) {
        m[ch] = __expf(m[ch] - M);
        L += lw[ch] * m[ch];
    }
    float inv = 1.0f / L;
#pragma unroll
    for (int p = 0; p < 4; ++p) {
        int i4 = lane + 64 * p;
        float4 s = make_float4(0.f, 0.f, 0.f, 0.f);
#pragma unroll
        for (int ch = 0; ch < NCH; ++ch) {
            float4 x = *(const float4*)(part + ((((size_t)ch * B_SZ) + b) * N_HEADS + h) * D_MODEL + 4 * i4);
            s.x = fmaf(m[ch], x.x, s.x);
            s.y = fmaf(m[ch], x.y, s.y);
            s.z = fmaf(m[ch], x.z, s.z);
            s.w = fmaf(m[ch], x.w, s.w);
        }
        s.x *= inv; s.y *= inv; s.z *= inv; s.w *= inv;
        *(float4*)(vt + 4 * i4) = s;
    }
    __syncthreads();
    const float* wv = Wv + h * D_K + lane;
    float acc = 0.f;
#pragma unroll 8
    for (int d = 0; d < D_MODEL; ++d) acc = fmaf(vt[d], wv[(size_t)d * D_MODEL], acc);
    cc[(size_t)b * D_MODEL + h * D_K + lane] = acc + bv[h * D_K + lane];
}

// ---------------- kernel 4: out[b,n] = relu(cc[b,:] @ Wo[:,n] + bo[n]) ----------------
// grid 256 = (64 b x 4 n-chunks), block 256
__global__ __launch_bounds__(256) void k_out(const float* __restrict__ cc,
                                             const float* __restrict__ Wo,
                                             const float* __restrict__ bo,
                                             float* __restrict__ out) {
    int b = blockIdx.x >> 2, nc = blockIdx.x & 3;
    int t = threadIdx.x;
    __shared__ float cl[D_MODEL];
    ((float4*)cl)[t] = ((const float4*)(cc + (size_t)b * D_MODEL))[t];
    __syncthreads();
    int n = nc * 256 + t;
    const float* w = Wo + n;
    float acc = 0.f;
#pragma unroll 8
    for (int m = 0; m < D_MODEL; ++m) acc = fmaf(cl[m], w[(size_t)m * D_MODEL], acc);
    float r = acc + bo[n];
    out[(size_t)b * D_MODEL + n] = r > 0.f ? r : 0.f;
}

extern "C" void kernel_launch(void* const* d_in, const int* in_sizes, int n_in,
                              void* d_out, int out_size, void* d_ws, size_t ws_size,
                              hipStream_t stream) {
    const float* q  = (const float*)d_in[0];
    const float* k  = (const float*)d_in[1];
    const float* v  = (const float*)d_in[2];
    const float* Wq = (const float*)d_in[3];
    const float* bq = (const float*)d_in[4];
    const float* Wk = (const float*)d_in[5];
    // d_in[6] = bk: unused — softmax is shift-invariant, qh.bk is constant per (b,h) row
    const float* Wv = (const float*)d_in[7];
    const float* bv = (const float*)d_in[8];
    const float* Wo = (const float*)d_in[9];
    const float* bo = (const float*)d_in[10];
    float* out = (float*)d_out;

    float* ws = (float*)d_ws;
    float* qh   = ws;                       // 65,536 f
    float* qt   = qh + 65536;               // 1,048,576 f
    float* part = qt + 1048576;             // 16,777,216 f  (NCH*B*H*D_MODEL)
    float* ml   = part + 16777216;          // 32,768 f      (NCH*B*H*2)
    float* cc   = ml + 32768;               // 65,536 f      (total ~72 MB)

    k_qh<<<256, 256, 0, stream>>>(q, Wq, bq, qh);
    k_qtil<<<1024, 256, 0, stream>>>(qh, Wk, qt);
    k_attn<<<1024, 256, 0, stream>>>(k, v, qt, part, ml);
    k_cc<<<1024, 64, 0, stream>>>(part, ml, Wv, bv, cc);
    k_out<<<256, 256, 0, stream>>>(cc, Wo, bo, out);
}

// Round 2
// 1343.085 us; speedup vs baseline: 1.1786x; 1.1786x over previous
//
#include <hip/hip_runtime.h>
#include <math.h>

#define D_MODEL 1024
#define N_HEADS 16
#define D_K 64
#define B_SZ 64
#define S_LEN 2048

// ---------------- kernel 0: qh[b,n] = q[b,:] @ Wq[:,n] + bq[n] ----------------
// grid 256 = (64 b x 4 n-chunks), block 256
__global__ __launch_bounds__(256) void k_qh(const float* __restrict__ q,
                                            const float* __restrict__ Wq,
                                            const float* __restrict__ bq,
                                            float* __restrict__ qh) {
    int b = blockIdx.x >> 2;
    int nc = blockIdx.x & 3;
    int t = threadIdx.x;
    __shared__ float ql[D_MODEL];
    ((float4*)ql)[t] = ((const float4*)(q + (size_t)b * D_MODEL))[t];
    __syncthreads();
    int n = nc * 256 + t;
    const float* w = Wq + n;
    float acc = 0.f;
#pragma unroll 8
    for (int d = 0; d < D_MODEL; ++d) acc = fmaf(ql[d], w[(size_t)d * D_MODEL], acc);
    qh[(size_t)b * D_MODEL + n] = acc + bq[n];
}

// ---------------- kernel 1: qt[b,h,d] = (1/8) * sum_j qh[b,h*64+j] * Wk[d, h*64+j] ----------------
// grid 1024 = (b,h), block 256; thread covers d = t + 256p
__global__ __launch_bounds__(256) void k_qtil(const float* __restrict__ qh,
                                              const float* __restrict__ Wk,
                                              float* __restrict__ qt) {
    int b = blockIdx.x >> 4;
    int h = blockIdx.x & 15;
    int t = threadIdx.x;
    __shared__ float qhl[D_K];
    if (t < 16) ((float4*)qhl)[t] = ((const float4*)(qh + (size_t)b * D_MODEL + h * D_K))[t];
    __syncthreads();
#pragma unroll
    for (int p = 0; p < 4; ++p) {
        int d = p * 256 + t;
        const float* w = Wk + (size_t)d * D_MODEL + h * D_K;
        float acc = 0.f;
#pragma unroll
        for (int j4 = 0; j4 < 16; ++j4) {
            float4 w4 = ((const float4*)w)[j4];
            float4 q4 = ((const float4*)qhl)[j4];
            acc += w4.x * q4.x + w4.y * q4.y + w4.z * q4.z + w4.w * q4.w;
        }
        qt[((size_t)(b * N_HEADS + h)) * D_MODEL + d] = acc * 0.125f;
    }
}

// ---------------- kernel 2: fused flash-decode chunk ----------------
// grid 1024 = (64 b x 16 s-chunks of 128), block 512 = 8 waves.
// Phase A: wave w -> heads 2w,2w+1; lane owns s = lane, 64+lane. 2x2 reg tile.
// Phase B: per-head chunk max m / sum l, p = exp(s-m) -> LDS
// Phase C: thread (t&255) owns d-float4, (t>>8) picks head-group of 8.
//          oacc[8] = 32 VGPRs -> no spill (round-1 lesson: 16-head accum at
//          256 thr spilled ~900 MB of scratch to HBM, 570 us).
#define NCH 16
#define CS 128
#define DCA 64
#define KROWA 68  // 17 quads/row (odd) -> b128 quad = (lane + d4) % 8: conflict-free
__global__ __launch_bounds__(512, 4) void k_attn(const float* __restrict__ k,
                                                 const float* __restrict__ v,
                                                 const float* __restrict__ qt,
                                                 float* __restrict__ part,
                                                 float* __restrict__ ml) {
    __shared__ float smem[CS * KROWA + N_HEADS * DCA];  // 38.9 KB
    float* kt = smem;
    float* qtl = smem + CS * KROWA;
    float* pl = smem;  // aliases kt region after score phase (8 KB << 34 KB)

    int b = blockIdx.x >> 4;
    int ch = blockIdx.x & 15;
    int t = threadIdx.x;
    int w = t >> 6, lane = t & 63;
    int s0 = ch * CS;
    const float* kbase = k + ((size_t)b * S_LEN + s0) * D_MODEL;
    const float* qtbase = qt + (size_t)b * N_HEADS * D_MODEL;

    float acc[2][2] = {};
    for (int dc = 0; dc < D_MODEL; dc += DCA) {
        // stage K tile: 128 s x 64 d ; 4 float4/thread ; 16 lanes per row (256B segs)
#pragma unroll
        for (int p = 0; p < 4; ++p) {
            int idx = t + 512 * p;
            int s = idx >> 4, d4 = idx & 15;
            float4 x = *(const float4*)(kbase + (size_t)s * D_MODEL + dc + 4 * d4);
            *(float4*)(kt + s * KROWA + 4 * d4) = x;
        }
        // stage qt tile: 16 h x 64 d (threads 0..255, one float4 each)
        if (t < 256) {
            int h = t >> 4, d4 = t & 15;
            *(float4*)(qtl + h * DCA + 4 * d4) =
                *(const float4*)(qtbase + (size_t)h * D_MODEL + dc + 4 * d4);
        }
        __syncthreads();
#pragma unroll
        for (int d4 = 0; d4 < DCA / 4; ++d4) {
            float4 qv[2], kv[2];
#pragma unroll
            for (int j = 0; j < 2; ++j) qv[j] = *(const float4*)(qtl + (2 * w + j) * DCA + 4 * d4);
#pragma unroll
            for (int i = 0; i < 2; ++i) kv[i] = *(const float4*)(kt + (64 * i + lane) * KROWA + 4 * d4);
#pragma unroll
            for (int i = 0; i < 2; ++i)
#pragma unroll
                for (int j = 0; j < 2; ++j)
                    acc[i][j] = fmaf(kv[i].x, qv[j].x,
                                fmaf(kv[i].y, qv[j].y,
                                fmaf(kv[i].z, qv[j].z,
                                fmaf(kv[i].w, qv[j].w, acc[i][j]))));
        }
        __syncthreads();
    }
    // ---- phase B: per-head chunk softmax partials (head 2w+j owned by wave w) ----
#pragma unroll
    for (int j = 0; j < 2; ++j) {
        float m = fmaxf(acc[0][j], acc[1][j]);
#pragma unroll
        for (int o = 32; o; o >>= 1) m = fmaxf(m, __shfl_xor(m, o, 64));
        float p0 = __expf(acc[0][j] - m);
        float p1 = __expf(acc[1][j] - m);
        float l = p0 + p1;
#pragma unroll
        for (int o = 32; o; o >>= 1) l += __shfl_xor(l, o, 64);
        int h = 2 * w + j;
        pl[h * CS + lane] = p0;
        pl[h * CS + 64 + lane] = p1;
        if (lane == 0) {
            float* mlp = ml + ((((size_t)ch * B_SZ) + b) * N_HEADS + h) * 2;
            mlp[0] = m;
            mlp[1] = l;
        }
    }
    __syncthreads();
    // ---- phase C: partial AV; thread owns d-float4 (t&255) for 8 heads (t>>8) ----
    int d4i = t & 255;
    int hg = t >> 8;  // 0 or 1 -> heads hg*8 .. hg*8+7
    float4 oacc[8];
#pragma unroll
    for (int hh = 0; hh < 8; ++hh) oacc[hh] = make_float4(0.f, 0.f, 0.f, 0.f);
    const float* vbase = v + ((size_t)b * S_LEN + s0) * D_MODEL + 4 * d4i;
    const float* plb = pl + (hg * 8) * CS;
    for (int sg = 0; sg < CS / 4; ++sg) {
        float4 v0 = *(const float4*)(vbase + (size_t)(4 * sg + 0) * D_MODEL);
        float4 v1 = *(const float4*)(vbase + (size_t)(4 * sg + 1) * D_MODEL);
        float4 v2 = *(const float4*)(vbase + (size_t)(4 * sg + 2) * D_MODEL);
        float4 v3 = *(const float4*)(vbase + (size_t)(4 * sg + 3) * D_MODEL);
#pragma unroll
        for (int hh = 0; hh < 8; ++hh) {
            float4 a4 = *(const float4*)(plb + hh * CS + 4 * sg);  // wave-uniform broadcast
            oacc[hh].x = fmaf(a4.x, v0.x, fmaf(a4.y, v1.x, fmaf(a4.z, v2.x, fmaf(a4.w, v3.x, oacc[hh].x))));
            oacc[hh].y = fmaf(a4.x, v0.y, fmaf(a4.y, v1.y, fmaf(a4.z, v2.y, fmaf(a4.w, v3.y, oacc[hh].y))));
            oacc[hh].z = fmaf(a4.x, v0.z, fmaf(a4.y, v1.z, fmaf(a4.z, v2.z, fmaf(a4.w, v3.z, oacc[hh].z))));
            oacc[hh].w = fmaf(a4.x, v0.w, fmaf(a4.y, v1.w, fmaf(a4.z, v2.w, fmaf(a4.w, v3.w, oacc[hh].w))));
        }
    }
#pragma unroll
    for (int hh = 0; hh < 8; ++hh)
        *(float4*)(part + ((((size_t)ch * B_SZ) + b) * N_HEADS + hg * 8 + hh) * D_MODEL + 4 * d4i) = oacc[hh];
}

// ---------------- kernel 3: cross-chunk combine + Wv projection ----------------
// grid 1024 = (b,h), block 64 (1 wave)
// vt[d] = (1/L) * sum_ch exp(m_ch - M) * part[ch,b,h,d]; cc = vt @ Wv[:,h64+lane] + bv
__global__ __launch_bounds__(64) void k_cc(const float* __restrict__ part,
                                           const float* __restrict__ ml,
                                           const float* __restrict__ Wv,
                                           const float* __restrict__ bv,
                                           float* __restrict__ cc) {
    int b = blockIdx.x >> 4, h = blockIdx.x & 15;
    int lane = threadIdx.x;
    __shared__ float vt[D_MODEL];
    float m[NCH], lw[NCH];
    float M = -3.4e38f;
#pragma unroll
    for (int ch = 0; ch < NCH; ++ch) {
        const float* mlp = ml + ((((size_t)ch * B_SZ) + b) * N_HEADS + h) * 2;
        m[ch] = mlp[0];
        lw[ch] = mlp[1];
        M = fmaxf(M, m[ch]);
    }
    float L = 0.f;
#pragma unroll
    for (int ch = 0; ch < NCH; ++ch) {
        m[ch] = __expf(m[ch] - M);
        L += lw[ch] * m[ch];
    }
    float inv = 1.0f / L;
#pragma unroll
    for (int p = 0; p < 4; ++p) {
        int i4 = lane + 64 * p;
        float4 s = make_float4(0.f, 0.f, 0.f, 0.f);
#pragma unroll
        for (int ch = 0; ch < NCH; ++ch) {
            float4 x = *(const float4*)(part + ((((size_t)ch * B_SZ) + b) * N_HEADS + h) * D_MODEL + 4 * i4);
            s.x = fmaf(m[ch], x.x, s.x);
            s.y = fmaf(m[ch], x.y, s.y);
            s.z = fmaf(m[ch], x.z, s.z);
            s.w = fmaf(m[ch], x.w, s.w);
        }
        s.x *= inv; s.y *= inv; s.z *= inv; s.w *= inv;
        *(float4*)(vt + 4 * i4) = s;
    }
    __syncthreads();
    const float* wv = Wv + h * D_K + lane;
    float acc = 0.f;
#pragma unroll 8
    for (int d = 0; d < D_MODEL; ++d) acc = fmaf(vt[d], wv[(size_t)d * D_MODEL], acc);
    cc[(size_t)b * D_MODEL + h * D_K + lane] = acc + bv[h * D_K + lane];
}

// ---------------- kernel 4: out[b,n] = relu(cc[b,:] @ Wo[:,n] + bo[n]) ----------------
// grid 256 = (64 b x 4 n-chunks), block 256
__global__ __launch_bounds__(256) void k_out(const float* __restrict__ cc,
                                             const float* __restrict__ Wo,
                                             const float* __restrict__ bo,
                                             float* __restrict__ out) {
    int b = blockIdx.x >> 2, nc = blockIdx.x & 3;
    int t = threadIdx.x;
    __shared__ float cl[D_MODEL];
    ((float4*)cl)[t] = ((const float4*)(cc + (size_t)b * D_MODEL))[t];
    __syncthreads();
    int n = nc * 256 + t;
    const float* w = Wo + n;
    float acc = 0.f;
#pragma unroll 8
    for (int m = 0; m < D_MODEL; ++m) acc = fmaf(cl[m], w[(size_t)m * D_MODEL], acc);
    float r = acc + bo[n];
    out[(size_t)b * D_MODEL + n] = r > 0.f ? r : 0.f;
}

extern "C" void kernel_launch(void* const* d_in, const int* in_sizes, int n_in,
                              void* d_out, int out_size, void* d_ws, size_t ws_size,
                              hipStream_t stream) {
    const float* q  = (const float*)d_in[0];
    const float* k  = (const float*)d_in[1];
    const float* v  = (const float*)d_in[2];
    const float* Wq = (const float*)d_in[3];
    const float* bq = (const float*)d_in[4];
    const float* Wk = (const float*)d_in[5];
    // d_in[6] = bk: unused — softmax is shift-invariant, qh.bk is constant per (b,h) row
    const float* Wv = (const float*)d_in[7];
    const float* bv = (const float*)d_in[8];
    const float* Wo = (const float*)d_in[9];
    const float* bo = (const float*)d_in[10];
    float* out = (float*)d_out;

    float* ws = (float*)d_ws;
    float* qh   = ws;                       // 65,536 f
    float* qt   = qh + 65536;               // 1,048,576 f
    float* part = qt + 1048576;             // 16,777,216 f  (NCH*B*H*D_MODEL)
    float* ml   = part + 16777216;          // 32,768 f      (NCH*B*H*2)
    float* cc   = ml + 32768;               // 65,536 f      (total ~72 MB)

    k_qh<<<256, 256, 0, stream>>>(q, Wq, bq, qh);
    k_qtil<<<1024, 256, 0, stream>>>(qh, Wk, qt);
    k_attn<<<1024, 512, 0, stream>>>(k, v, qt, part, ml);
    k_cc<<<1024, 64, 0, stream>>>(part, ml, Wv, bv, cc);
    k_out<<<256, 256, 0, stream>>>(cc, Wo, bo, out);
}

// Round 3
// 1342.046 us; speedup vs baseline: 1.1795x; 1.0008x over previous
//
#include <hip/hip_runtime.h>
#include <math.h>

#define D_MODEL 1024
#define N_HEADS 16
#define D_K 64
#define B_SZ 64
#define S_LEN 2048

// ---------------- kernel 0: qh[b,n] = q[b,:] @ Wq[:,n] + bq[n] ----------------
__global__ __launch_bounds__(256) void k_qh(const float* __restrict__ q,
                                            const float* __restrict__ Wq,
                                            const float* __restrict__ bq,
                                            float* __restrict__ qh) {
    int b = blockIdx.x >> 2;
    int nc = blockIdx.x & 3;
    int t = threadIdx.x;
    __shared__ float ql[D_MODEL];
    ((float4*)ql)[t] = ((const float4*)(q + (size_t)b * D_MODEL))[t];
    __syncthreads();
    int n = nc * 256 + t;
    const float* w = Wq + n;
    float acc = 0.f;
#pragma unroll 8
    for (int d = 0; d < D_MODEL; ++d) acc = fmaf(ql[d], w[(size_t)d * D_MODEL], acc);
    qh[(size_t)b * D_MODEL + n] = acc + bq[n];
}

// ---------------- kernel 1: qt[b,h,d] = (1/8) * sum_j qh[b,h*64+j] * Wk[d, h*64+j] ----------------
__global__ __launch_bounds__(256) void k_qtil(const float* __restrict__ qh,
                                              const float* __restrict__ Wk,
                                              float* __restrict__ qt) {
    int b = blockIdx.x >> 4;
    int h = blockIdx.x & 15;
    int t = threadIdx.x;
    __shared__ float qhl[D_K];
    if (t < 16) ((float4*)qhl)[t] = ((const float4*)(qh + (size_t)b * D_MODEL + h * D_K))[t];
    __syncthreads();
#pragma unroll
    for (int p = 0; p < 4; ++p) {
        int d = p * 256 + t;
        const float* w = Wk + (size_t)d * D_MODEL + h * D_K;
        float acc = 0.f;
#pragma unroll
        for (int j4 = 0; j4 < 16; ++j4) {
            float4 w4 = ((const float4*)w)[j4];
            float4 q4 = ((const float4*)qhl)[j4];
            acc += w4.x * q4.x + w4.y * q4.y + w4.z * q4.z + w4.w * q4.w;
        }
        qt[((size_t)(b * N_HEADS + h)) * D_MODEL + d] = acc * 0.125f;
    }
}

// ---------------- kernel 2: fused flash-decode chunk ----------------
// grid 1024 = (64 b x 16 s-chunks of 128), block 512 = 8 waves.
// Phase A: wave w -> head quad (w&3), d-half (w>>2). qt operand comes from
//          GLOBAL via wave-uniform (readfirstlane) pointer -> s_load_dwordx4,
//          zero LDS traffic for qt. kt LDS read per wave halves via d-split.
//          (round-2 lesson: 8 waves re-reading full kt + LDS-broadcast qt made
//          the kernel LDS-issue-bound at 23% HBM / 29% VALU.)
// Phase A': cross-wave d-half reduction of scores through 8 KB LDS scratch.
// Phase B: waves 0-3 compute per-head chunk max/sum, p = exp(s-m) -> pl.
// Phase C: thread (t&255) owns d-float4, (t>>8) picks head-group of 8;
//          oacc[8] = 32 VGPRs (no spill — round-1 lesson).
#define NCH 16
#define CS 128
#define DCA 64
#define KROWA 68  // 17 quads/row (odd) -> b128 quad = (lane + c) % 8: conflict-free
__global__ __launch_bounds__(512, 4) void k_attn(const float* __restrict__ k,
                                                 const float* __restrict__ v,
                                                 const float* __restrict__ qt,
                                                 float* __restrict__ part,
                                                 float* __restrict__ ml) {
    __shared__ float smem[CS * KROWA];  // 34.8 KB; re-used as pl (8 KB) + red (8 KB)
    float* kt = smem;
    float* pl = smem;                   // [16 h][128 s] after phase A
    float* red = smem + N_HEADS * CS;   // [4 hq][2 i][4 j][64 lane] scratch

    int b = blockIdx.x >> 4;
    int ch = blockIdx.x & 15;
    int t = threadIdx.x;
    int w = t >> 6, lane = t & 63;
    int s0 = ch * CS;
    const float* kbase = k + ((size_t)b * S_LEN + s0) * D_MODEL;

    // wave-uniform head-quad / d-half (SGPR-hoisted so qt loads scalarize)
    int wu = __builtin_amdgcn_readfirstlane(w);
    int hq = wu & 3, dh = wu >> 2;
    const float* q0 = qt + (size_t)(b * N_HEADS + hq * 4) * D_MODEL + dh * (DCA / 2);

    float acc[2][4] = {};
    for (int dc = 0; dc < D_MODEL; dc += DCA) {
        // stage K tile: 128 s x 64 d ; 4 float4/thread ; 16 lanes per row (256B segs)
#pragma unroll
        for (int p = 0; p < 4; ++p) {
            int idx = t + 512 * p;
            int s = idx >> 4, d4 = idx & 15;
            float4 x = *(const float4*)(kbase + (size_t)s * D_MODEL + dc + 4 * d4);
            *(float4*)(kt + s * KROWA + 4 * d4) = x;
        }
        __syncthreads();
        const float* ktd = kt + dh * (DCA / 2);
#pragma unroll
        for (int d4 = 0; d4 < 8; ++d4) {
            float4 qv[4];
#pragma unroll
            for (int j = 0; j < 4; ++j)
                qv[j] = *(const float4*)(q0 + (size_t)j * D_MODEL + dc + 4 * d4);  // s_load
            float4 kv[2];
#pragma unroll
            for (int i = 0; i < 2; ++i)
                kv[i] = *(const float4*)(ktd + (64 * i + lane) * KROWA + 4 * d4);
#pragma unroll
            for (int i = 0; i < 2; ++i)
#pragma unroll
                for (int j = 0; j < 4; ++j)
                    acc[i][j] = fmaf(kv[i].x, qv[j].x,
                                fmaf(kv[i].y, qv[j].y,
                                fmaf(kv[i].z, qv[j].z,
                                fmaf(kv[i].w, qv[j].w, acc[i][j]))));
        }
        __syncthreads();
    }
    // ---- phase A': combine d-halves (waves 4-7 hold the upper-d partials) ----
    if (dh == 1) {
#pragma unroll
        for (int i = 0; i < 2; ++i)
#pragma unroll
            for (int j = 0; j < 4; ++j)
                red[((((hq * 2 + i) * 4) + j) << 6) | lane] = acc[i][j];
    }
    __syncthreads();
    // ---- phase B: per-head chunk softmax partials (waves 0-3, 4 heads each) ----
    if (dh == 0) {
#pragma unroll
        for (int j = 0; j < 4; ++j) {
            float a0 = acc[0][j] + red[((((hq * 2 + 0) * 4) + j) << 6) | lane];
            float a1 = acc[1][j] + red[((((hq * 2 + 1) * 4) + j) << 6) | lane];
            float m = fmaxf(a0, a1);
#pragma unroll
            for (int o = 32; o; o >>= 1) m = fmaxf(m, __shfl_xor(m, o, 64));
            float p0 = __expf(a0 - m);
            float p1 = __expf(a1 - m);
            float l = p0 + p1;
#pragma unroll
            for (int o = 32; o; o >>= 1) l += __shfl_xor(l, o, 64);
            int h = hq * 4 + j;
            pl[h * CS + lane] = p0;
            pl[h * CS + 64 + lane] = p1;
            if (lane == 0) {
                float* mlp = ml + ((((size_t)ch * B_SZ) + b) * N_HEADS + h) * 2;
                mlp[0] = m;
                mlp[1] = l;
            }
        }
    }
    __syncthreads();
    // ---- phase C: partial AV; thread owns d-float4 (t&255) for 8 heads (t>>8) ----
    int d4i = t & 255;
    int hg = t >> 8;  // 0 or 1 -> heads hg*8 .. hg*8+7
    float4 oacc[8];
#pragma unroll
    for (int hh = 0; hh < 8; ++hh) oacc[hh] = make_float4(0.f, 0.f, 0.f, 0.f);
    const float* vbase = v + ((size_t)b * S_LEN + s0) * D_MODEL + 4 * d4i;
    const float* plb = pl + (hg * 8) * CS;
    for (int sg = 0; sg < CS / 4; ++sg) {
        float4 v0 = *(const float4*)(vbase + (size_t)(4 * sg + 0) * D_MODEL);
        float4 v1 = *(const float4*)(vbase + (size_t)(4 * sg + 1) * D_MODEL);
        float4 v2 = *(const float4*)(vbase + (size_t)(4 * sg + 2) * D_MODEL);
        float4 v3 = *(const float4*)(vbase + (size_t)(4 * sg + 3) * D_MODEL);
#pragma unroll
        for (int hh = 0; hh < 8; ++hh) {
            float4 a4 = *(const float4*)(plb + hh * CS + 4 * sg);  // wave-uniform broadcast
            oacc[hh].x = fmaf(a4.x, v0.x, fmaf(a4.y, v1.x, fmaf(a4.z, v2.x, fmaf(a4.w, v3.x, oacc[hh].x))));
            oacc[hh].y = fmaf(a4.x, v0.y, fmaf(a4.y, v1.y, fmaf(a4.z, v2.y, fmaf(a4.w, v3.y, oacc[hh].y))));
            oacc[hh].z = fmaf(a4.x, v0.z, fmaf(a4.y, v1.z, fmaf(a4.z, v2.z, fmaf(a4.w, v3.z, oacc[hh].z))));
            oacc[hh].w = fmaf(a4.x, v0.w, fmaf(a4.y, v1.w, fmaf(a4.z, v2.w, fmaf(a4.w, v3.w, oacc[hh].w))));
        }
    }
#pragma unroll
    for (int hh = 0; hh < 8; ++hh)
        *(float4*)(part + ((((size_t)ch * B_SZ) + b) * N_HEADS + hg * 8 + hh) * D_MODEL + 4 * d4i) = oacc[hh];
}

// ---------------- kernel 3: cross-chunk combine + Wv projection ----------------
__global__ __launch_bounds__(64) void k_cc(const float* __restrict__ part,
                                           const float* __restrict__ ml,
                                           const float* __restrict__ Wv,
                                           const float* __restrict__ bv,
                                           float* __restrict__ cc) {
    int b = blockIdx.x >> 4, h = blockIdx.x & 15;
    int lane = threadIdx.x;
    __shared__ float vt[D_MODEL];
    float m[NCH], lw[NCH];
    float M = -3.4e38f;
#pragma unroll
    for (int ch = 0; ch < NCH; ++ch) {
        const float* mlp = ml + ((((size_t)ch * B_SZ) + b) * N_HEADS + h) * 2;
        m[ch] = mlp[0];
        lw[ch] = mlp[1];
        M = fmaxf(M, m[ch]);
    }
    float L = 0.f;
#pragma unroll
    for (int ch = 0; ch < NCH; ++ch) {
        m[ch] = __expf(m[ch] - M);
        L += lw[ch] * m[ch];
    }
    float inv = 1.0f / L;
#pragma unroll
    for (int p = 0; p < 4; ++p) {
        int i4 = lane + 64 * p;
        float4 s = make_float4(0.f, 0.f, 0.f, 0.f);
#pragma unroll
        for (int ch = 0; ch < NCH; ++ch) {
            float4 x = *(const float4*)(part + ((((size_t)ch * B_SZ) + b) * N_HEADS + h) * D_MODEL + 4 * i4);
            s.x = fmaf(m[ch], x.x, s.x);
            s.y = fmaf(m[ch], x.y, s.y);
            s.z = fmaf(m[ch], x.z, s.z);
            s.w = fmaf(m[ch], x.w, s.w);
        }
        s.x *= inv; s.y *= inv; s.z *= inv; s.w *= inv;
        *(float4*)(vt + 4 * i4) = s;
    }
    __syncthreads();
    const float* wv = Wv + h * D_K + lane;
    float acc = 0.f;
#pragma unroll 8
    for (int d = 0; d < D_MODEL; ++d) acc = fmaf(vt[d], wv[(size_t)d * D_MODEL], acc);
    cc[(size_t)b * D_MODEL + h * D_K + lane] = acc + bv[h * D_K + lane];
}

// ---------------- kernel 4: out[b,n] = relu(cc[b,:] @ Wo[:,n] + bo[n]) ----------------
__global__ __launch_bounds__(256) void k_out(const float* __restrict__ cc,
                                             const float* __restrict__ Wo,
                                             const float* __restrict__ bo,
                                             float* __restrict__ out) {
    int b = blockIdx.x >> 2, nc = blockIdx.x & 3;
    int t = threadIdx.x;
    __shared__ float cl[D_MODEL];
    ((float4*)cl)[t] = ((const float4*)(cc + (size_t)b * D_MODEL))[t];
    __syncthreads();
    int n = nc * 256 + t;
    const float* w = Wo + n;
    float acc = 0.f;
#pragma unroll 8
    for (int m = 0; m < D_MODEL; ++m) acc = fmaf(cl[m], w[(size_t)m * D_MODEL], acc);
    float r = acc + bo[n];
    out[(size_t)b * D_MODEL + n] = r > 0.f ? r : 0.f;
}

extern "C" void kernel_launch(void* const* d_in, const int* in_sizes, int n_in,
                              void* d_out, int out_size, void* d_ws, size_t ws_size,
                              hipStream_t stream) {
    const float* q  = (const float*)d_in[0];
    const float* k  = (const float*)d_in[1];
    const float* v  = (const float*)d_in[2];
    const float* Wq = (const float*)d_in[3];
    const float* bq = (const float*)d_in[4];
    const float* Wk = (const float*)d_in[5];
    // d_in[6] = bk: unused — softmax is shift-invariant, qh.bk is constant per (b,h) row
    const float* Wv = (const float*)d_in[7];
    const float* bv = (const float*)d_in[8];
    const float* Wo = (const float*)d_in[9];
    const float* bo = (const float*)d_in[10];
    float* out = (float*)d_out;

    float* ws = (float*)d_ws;
    float* qh   = ws;                       // 65,536 f
    float* qt   = qh + 65536;               // 1,048,576 f
    float* part = qt + 1048576;             // 16,777,216 f  (NCH*B*H*D_MODEL)
    float* ml   = part + 16777216;          // 32,768 f      (NCH*B*H*2)
    float* cc   = ml + 32768;               // 65,536 f      (total ~72 MB)

    k_qh<<<256, 256, 0, stream>>>(q, Wq, bq, qh);
    k_qtil<<<1024, 256, 0, stream>>>(qh, Wk, qt);
    k_attn<<<1024, 512, 0, stream>>>(k, v, qt, part, ml);
    k_cc<<<1024, 64, 0, stream>>>(part, ml, Wv, bv, cc);
    k_out<<<256, 256, 0, stream>>>(cc, Wo, bo, out);
}